// Round 21
// baseline (297.212 us; speedup 1.0000x reference)
//
#include <hip/hip_runtime.h>
#include <hip/hip_bf16.h>

#define NB 180
typedef __attribute__((ext_vector_type(8))) short short8;
typedef __attribute__((ext_vector_type(4))) float f32x4;
typedef unsigned short ushort_t;

__device__ __forceinline__ void gload16(const void* src, void* lds_base){
    __builtin_amdgcn_global_load_lds(
        (const __attribute__((address_space(1))) unsigned int*)src,
        (__attribute__((address_space(3))) unsigned int*)lds_base, 16, 0, 0);
}

__device__ __forceinline__ ushort_t f2bu(float v){
    __hip_bfloat16 h = __float2bfloat16(v);
    return *(ushort_t*)&h;
}

__device__ __forceinline__ float bu2f(ushort_t v){
    union { unsigned int u; float f; } cv;
    cv.u = ((unsigned int)v) << 16;
    return cv.f;
}

// caps_w fp32 [oc][ic256*81] -> bpack bf16 [gk=kk*32+icg][oc][j], via LDS transpose.
__global__ __launch_bounds__(256) void build_bpack_t(const float* __restrict__ w,
                                                     __hip_bfloat16* __restrict__ bpack){
    __shared__ float ls[10368];                 // 128 ic x 81 kk
    int oc = blockIdx.x, ich = blockIdx.y, t = threadIdx.x;
    const float4* src = (const float4*)(w + (size_t)oc * 20736 + ich * 10368);
    for (int i = t; i < 2592; i += 256) ((float4*)ls)[i] = src[i];
    __syncthreads();
    for (int idx = t; idx < 10368; idx += 256){
        int j = idx & 7, icg = (idx >> 3) & 15, kk = idx >> 7;
        bpack[(size_t)(kk * 32 + ich * 16 + icg) * 2048 + oc * 8 + j] =
            __float2bfloat16(ls[(icg * 8 + j) * 81 + kk]);
    }
}

// W_route fp32 -> W2 [o][ki][d]; ALSO builds wpack1 (conv1 weights) and zeroes bij.
// grid 96, block 256.
__global__ __launch_bounds__(256) void build_w2(const float* __restrict__ Wr, float* __restrict__ W2,
                                                const float* __restrict__ cw1, __hip_bfloat16* __restrict__ wpack1,
                                                float* __restrict__ bij){
    __shared__ float ls[15360];                 // 12 i x 1280
    int bid = blockIdx.x;
    int i0 = bid * 12, t = threadIdx.x;
    const float4* src = (const float4*)(Wr + (size_t)i0 * 1280);
    for (int w = t; w < 3840; w += 256) ((float4*)ls)[w] = src[w];
    // wpack1: element idx = bid*256 + t (24576 total)
    {
        int e = bid * 256 + t;
        int j = e & 7, oc = (e >> 3) & 255, gg = e >> 11;   // gg = ks*4+g
        int k = (gg >> 2) * 32 + (gg & 3) * 8 + j;
        float v = (k < 81) ? cw1[oc * 81 + k] : 0.f;
        wpack1[e] = __float2bfloat16(v);
    }
    if (t < 120) bij[bid * 120 + t] = 0.f;      // 96*120 = 11520
    __syncthreads();
    for (int idx = t; idx < 15360; idx += 256){
        int d = idx & 15, r = idx >> 4;
        int il = r % 12, ok = r / 12;           // ok = o*8+k
        int k = ok & 7, o = ok >> 3;
        W2[(size_t)o * 147456 + (size_t)(k * 1152 + i0 + il) * 16 + d] =
            ls[il * 1280 + o * 128 + d * 8 + k];
    }
}

// conv1 as MFMA implicit-GEMM (r13 verbatim): 112 px x 256 oc per block, K=96.
__global__ __launch_bounds__(256) void conv1_mfma(const float* __restrict__ x,
                                                  const __hip_bfloat16* __restrict__ wpack1,
                                                  const float* __restrict__ bias,
                                                  __hip_bfloat16* __restrict__ hT){
    __shared__ ushort_t xs[784];
    __shared__ ushort_t ktab[96];
    int bid = blockIdx.x;
    int b = bid >> 2, mc = bid & 3;
    int t = threadIdx.x, lane = t & 63, wn = t >> 6;
    int g = lane >> 4, lr = lane & 15;

    for (int i = t; i < 784; i += 256) xs[i] = f2bu(x[b * 784 + i]);
    if (t < 96) ktab[t] = (t < 81) ? (ushort_t)((t / 9) * 28 + (t % 9)) : (ushort_t)0;
    __syncthreads();

    int p0 = mc * 112;
    int pbm[7];
#pragma unroll
    for (int m = 0; m < 7; m++){
        int p = p0 + m * 16 + lr;
        p = p < 400 ? p : 399;
        pbm[m] = (p / 20) * 28 + (p % 20);
    }

    f32x4 acc[7][4];
#pragma unroll
    for (int m = 0; m < 7; m++)
#pragma unroll
        for (int n = 0; n < 4; n++) acc[m][n] = (f32x4){0.f, 0.f, 0.f, 0.f};

#pragma unroll
    for (int ks = 0; ks < 3; ks++){
        short8 ko = *(const short8*)&ktab[ks * 32 + g * 8];
        short8 bf[4];
#pragma unroll
        for (int n = 0; n < 4; n++)
            bf[n] = *(const short8*)(wpack1 + (size_t)(((ks * 4 + g) * 256) + wn * 64 + n * 16 + lr) * 8);
#pragma unroll
        for (int m = 0; m < 7; m++){
            short8 af;
#pragma unroll
            for (int e = 0; e < 8; e++)
                af[e] = (short)xs[pbm[m] + (int)(ushort_t)ko[e]];
#pragma unroll
            for (int n = 0; n < 4; n++)
                acc[m][n] = __builtin_amdgcn_mfma_f32_16x16x32_bf16(af, bf[n], acc[m][n], 0, 0, 0);
        }
    }

    float bv[4];
#pragma unroll
    for (int n = 0; n < 4; n++) bv[n] = bias[wn * 64 + n * 16 + lr];
#pragma unroll
    for (int m = 0; m < 7; m++){
#pragma unroll
        for (int rg = 0; rg < 4; rg++){
            int p = p0 + m * 16 + g * 4 + rg;
            if (p < 400){
#pragma unroll
                for (int n = 0; n < 4; n++){
                    float v = acc[m][n][rg] + bv[n];
                    v = v > 0.f ? v : 0.f;
                    hT[((size_t)b * 400 + p) * 256 + wn * 64 + n * 16 + lr] = __float2bfloat16(v);
                }
            }
        }
    }
}

// Implicit-GEMM capsconv — r19 verbatim (87.5 us): XCD remap + T5 setprio.
__global__ __launch_bounds__(256, 2) void capsconv_mfma(const __hip_bfloat16* __restrict__ hT,
                                                        const __hip_bfloat16* __restrict__ bpack,
                                                        float* __restrict__ part){
    extern __shared__ char smem[];               // 61440 B
    ushort_t* hsA = (ushort_t*)smem;

    int bid = blockIdx.x;
    int idx = (bid & 7) * 51 + (bid >> 3);
    if (idx >= 405) return;
    int mt = idx / 9, ky = idx - mt * 9;
    int b0 = mt * 4;
    int t = threadIdx.x, lane = t & 63, wn = t >> 6;
    int g = lane >> 4, lr = lane & 15;

    int pfm[9];
#pragma unroll
    for (int m = 0; m < 9; m++){
        int R = m * 16 + lr;
        int lb = R / 36, pos = R - lb * 36;
        int oy = pos / 6, ox = pos - oy * 6;
        int yy = lb * 6 + oy;
        pfm[m] = ((yy * 20 + 2 * ox) << 8) | (ox + 6 * yy);
    }
    int gbase = g * 2048 + wn * 512 + lr * 8;    // B lane offset (bf16 elems)

    auto stageA = [&](int a){
#pragma unroll
        for (int rnd = 0; rnd < 15; rnd++){
            int L = rnd * 256 + t;               // granule 0..3839
            int p = L >> 3, sg = L & 7;
            int yy = p / 20, xx = p - yy * 20;
            int lb = yy / 6;
            int y = ky + 2 * (yy - lb * 6);
            int f = ((xx >> 1) + 6 * yy) & 7;
            const __hip_bfloat16* src = hT + ((size_t)(((b0 + lb) * 20 + y) * 20 + xx) * 256
                                             + a * 64 + 8 * (sg ^ f));
            gload16(src, hsA + (size_t)(rnd * 256 + (t & ~63)) * 8);
        }
    };

    f32x4 acc[9][4];
#pragma unroll
    for (int m = 0; m < 9; m++)
#pragma unroll
        for (int n = 0; n < 4; n++) acc[m][n] = (f32x4){0.f, 0.f, 0.f, 0.f};

    stageA(0);
    __syncthreads();

    for (int a = 0; a < 4; a++){
#pragma unroll 2
        for (int r = 0; r < 18; r++){
            int kx = r >> 1, ics = r & 1;
            int ksg = (ky * 9 + kx) * 8 + 2 * a + ics;   // wave-uniform
            const __hip_bfloat16* bstep = bpack + (size_t)ksg * 8192 + gbase;
            short8 bf[4];
#pragma unroll
            for (int n = 0; n < 4; n++)
                bf[n] = *(const short8*)(bstep + n * 128);
            int jj = ics * 4 + g;
            __builtin_amdgcn_s_setprio(1);       // T5
#pragma unroll
            for (int m = 0; m < 9; m++){
                int pf = pfm[m];
                int p = (pf >> 8) + kx;
                int f = ((pf & 255) + (kx >> 1)) & 7;
                short8 af = *(const short8*)(hsA + (size_t)(p * 8 + (jj ^ f)) * 8);
#pragma unroll
                for (int n = 0; n < 4; n++)
                    acc[m][n] = __builtin_amdgcn_mfma_f32_16x16x32_bf16(af, bf[n], acc[m][n], 0, 0, 0);
            }
            __builtin_amdgcn_s_setprio(0);
        }
        if (a < 3){
            __syncthreads();     // all waves done reading chunk a
            stageA(a + 1);
            __syncthreads();     // drains gload16s + visibility
        }
    }

    // Epilogue: per-lb LDS transpose tile tl[pos 36][oc 260], conflict-free.
    float* tl = (float*)smem;
    size_t pbase = ((size_t)ky * 180 + b0) * 9216;
    for (int lb = 0; lb < 4; lb++){
        int rlo = lb * 36;
        __syncthreads();
#pragma unroll
        for (int m = 0; m < 9; m++){
#pragma unroll
            for (int n = 0; n < 4; n++){
                int oc = wn * 64 + n * 16 + lr;
#pragma unroll
                for (int rg = 0; rg < 4; rg++){
                    int row = m * 16 + g * 4 + rg;
                    if (row >= rlo && row < rlo + 36)
                        tl[(row - rlo) * 260 + oc] = acc[m][n][rg];
                }
            }
        }
        __syncthreads();
#pragma unroll
        for (int j = 0; j < 9; j++){
            int pos = j * 4;
            float4 vv;
            vv.x = tl[(pos    ) * 260 + t];
            vv.y = tl[(pos + 1) * 260 + t];
            vv.z = tl[(pos + 2) * 260 + t];
            vv.w = tl[(pos + 3) * 260 + t];
            *(float4*)&part[pbase + (size_t)lb * 9216 + t * 36 + pos] = vv;
        }
    }
}

// reduce 9 ky-partials + bias, squash over each (b,k) 1152-block, COALESCED write to u[b][ki].
__global__ __launch_bounds__(192) void reduce_squash(const float* __restrict__ part,
                                                     const float* __restrict__ caps_b,
                                                     float* __restrict__ u){
    __shared__ float red[3];
    int bk = blockIdx.x;
    int b = bk >> 3, k = bk & 7;
    int t = threadIdx.x;
    size_t base = (size_t)k * 1152;
    float vals[6];
    float ssq = 0.f;
#pragma unroll
    for (int j = 0; j < 6; j++){
        int i = t + j * 192;
        int oc = k * 32 + i / 36;
        float v = caps_b[oc];
#pragma unroll
        for (int kyi = 0; kyi < 9; kyi++)
            v += part[(size_t)(kyi * 180 + b) * 9216 + base + i];
        vals[j] = v; ssq += v * v;
    }
#pragma unroll
    for (int off = 32; off; off >>= 1) ssq += __shfl_down(ssq, off, 64);
    if ((t & 63) == 0) red[t >> 6] = ssq;
    __syncthreads();
    float tot = red[0] + red[1] + red[2];
    float scale = 1.f / (sqrtf(tot) + tot);
#pragma unroll
    for (int j = 0; j < 6; j++)
        u[(size_t)b * 9216 + base + t + j * 192] = vals[j] * scale;
}

// u [b][ki=9216] fp32 -> uTb [ki][b=180] bf16, coalesced 32x32 tiles.
__global__ __launch_bounds__(1024) void transpose_u(const float* __restrict__ u, ushort_t* __restrict__ uTb){
    __shared__ float tile[32][33];
    int ki0 = blockIdx.x * 32, b0 = blockIdx.y * 32;
    int tx = threadIdx.x, ty = threadIdx.y;
    int b = b0 + ty;
    if (b < NB) tile[ty][tx] = u[(size_t)b * 9216 + ki0 + tx];
    __syncthreads();
    int bw = b0 + tx;
    if (bw < NB) uTb[(size_t)(ki0 + ty) * NB + bw] = f2bu(tile[tx][ty]);
}

// split-K s-partials, softmax fused in; paired-o blocks; uT in bf16. (r19 verbatim)
__global__ __launch_bounds__(384) void s_partial2(const float* __restrict__ W2, const ushort_t* __restrict__ uTb,
                                                  const float* __restrict__ bij, float* __restrict__ part72,
                                                  int first){
    __shared__ float ws2[2][2048];
    __shared__ float cs[2][128];
    int op = blockIdx.x, kc = blockIdx.y, t = threadIdx.x;
    int grp = t / 192, tg = t - grp * 192;
    int o = op * 2 + grp;
    const float4* src = (const float4*)(W2 + (size_t)o * 147456 + (size_t)kc * 2048);
    for (int w = tg; w < 512; w += 192) ((float4*)ws2[grp])[w] = src[w];
    if (tg < 128){
        if (first){
            cs[grp][tg] = 0.1f;
        } else {
            int ki = kc * 128 + tg;
            int i = ki - (ki / 1152) * 1152;
            const float* bp = bij + (size_t)i * 10;
            float v[10]; float mx = -1e30f;
#pragma unroll
            for (int q = 0; q < 10; q++){ v[q] = bp[q]; mx = fmaxf(mx, v[q]); }
            float sum = 0.f;
#pragma unroll
            for (int q = 0; q < 10; q++){ v[q] = __expf(v[q] - mx); sum += v[q]; }
            cs[grp][tg] = v[o] / sum;
        }
    }
    __syncthreads();
    if (tg < NB){
        f32x4 a0 = {0,0,0,0}, a1 = {0,0,0,0}, a2 = {0,0,0,0}, a3 = {0,0,0,0};
        const ushort_t* up = uTb + (size_t)kc * 128 * NB + tg;
        const float* w2g = ws2[grp];
        const float* csg = cs[grp];
#pragma unroll 4
        for (int j = 0; j < 128; j++){
            float tmp = bu2f(up[j * NB]) * csg[j];
            const f32x4* wp = (const f32x4*)(w2g + j * 16);
            a0 += tmp * wp[0]; a1 += tmp * wp[1]; a2 += tmp * wp[2]; a3 += tmp * wp[3];
        }
        f32x4* pp = (f32x4*)(part72 + ((size_t)kc * NB + tg) * 160 + o * 16);
        pp[0] = a0; pp[1] = a1; pp[2] = a2; pp[3] = a3;
    }
}

// fused: s[b][od] = sum_kc part72[kc][b][od], 2-way kc-split across thread groups;
// v = s / (sqrt(msq)+msq), msq over o. grid 180, block 384.
__global__ __launch_bounds__(384) void sred_vsq(const float* __restrict__ part72, float* __restrict__ v){
    __shared__ float sv2[2][160];
    __shared__ float sc[16];
    int b = blockIdx.x, t = threadIdx.x;
    int h = t / 192, tg = t - h * 192;
    if (tg < 160){
        float s = 0.f;
        const float* pp = part72 + (size_t)b * 160 + tg + (size_t)(h * 36) * NB * 160;
        for (int kc = 0; kc < 36; kc++)
            s += pp[(size_t)kc * NB * 160];
        sv2[h][tg] = s;
    }
    __syncthreads();
    if (t < 16){
        float m = 0.f;
#pragma unroll
        for (int o = 0; o < 10; o++){
            float x = sv2[0][o * 16 + t] + sv2[1][o * 16 + t];
            m += x * x;
        }
        sc[t] = 1.f / (sqrtf(m) + m);
    }
    __syncthreads();
    if (t < 160) v[b * 160 + t] = (sv2[0][t] + sv2[1][t]) * sc[t & 15];
}

// fused p_gemm + uv_contract: P-tile in regs, dot with W2, atomicAdd into bij. (r20-proven)
__global__ __launch_bounds__(320) void p_uv(const ushort_t* __restrict__ uTb, const float* __restrict__ v,
                                            const float* __restrict__ W2, float* __restrict__ bij){
    __shared__ float vs[60 * 160];
    int t = threadIdx.x;
    int o = t % 10, kil = t / 10;
    int ki = blockIdx.x * 32 + kil;
    float acc[16];
#pragma unroll
    for (int d = 0; d < 16; d++) acc[d] = 0.f;
    const ushort_t* up = uTb + (size_t)ki * NB;
    for (int b0 = 0; b0 < NB; b0 += 60){
        __syncthreads();
        for (int j = t; j < 9600; j += 320) vs[j] = v[b0 * 160 + j];
        __syncthreads();
        for (int b = 0; b < 60; b++){
            float uv = bu2f(up[b0 + b]);
            const float* vp = &vs[b * 160 + o * 16];
#pragma unroll
            for (int d = 0; d < 16; d++) acc[d] += uv * vp[d];
        }
    }
    const float4* wp = (const float4*)(W2 + (size_t)o * 147456 + (size_t)ki * 16);
    float dot = 0.f;
#pragma unroll
    for (int q = 0; q < 4; q++){
        float4 a = wp[q];
        dot += a.x * acc[q*4] + a.y * acc[q*4+1] + a.z * acc[q*4+2] + a.w * acc[q*4+3];
    }
    int i = ki % 1152;
    atomicAdd(&bij[i * 10 + o], dot * (1.0f / 180.0f));
}

extern "C" void kernel_launch(void* const* d_in, const int* in_sizes, int n_in,
                              void* d_out, int out_size, void* d_ws, size_t ws_size,
                              hipStream_t stream){
    const float* x       = (const float*)d_in[0];
    const float* conv1_w = (const float*)d_in[1];
    const float* conv1_b = (const float*)d_in[2];
    const float* caps_w  = (const float*)d_in[3];
    const float* caps_b  = (const float*)d_in[4];
    const float* Wr      = (const float*)d_in[5];
    float* out = (float*)d_out;

    char* wsb = (char*)d_ws;
    __hip_bfloat16* hTb   = (__hip_bfloat16*)wsb;                  // 36,864,000 B
    __hip_bfloat16* bpack = (__hip_bfloat16*)(wsb + 36864000);     // 10,616,832 B
    float* part = (float*)(wsb + 36864000 + 10616832);             // 59,719,680 B
    float* u    = part + 14929920;                                 //  6,635,520 B
    ushort_t* uTb = (ushort_t*)(u + 1658880);                      //  3,317,760 B (bf16)
    __hip_bfloat16* wpack1 = (__hip_bfloat16*)((char*)uTb + 3317760); // 49,152 B

    // routing scratch aliases 'part' (dead after reduce_squash + transpose_u);
    // NOTE: W2/bij written by build_w2 AFTER part is dead in the stream order below.
    float* W2     = part;                     // 1,474,560 f
    float* part72 = W2 + 1474560;             // 2,073,600 f
    float* bij    = part72 + 2073600;         //    11,520 f

    hipFuncSetAttribute((const void*)capsconv_mfma,
                        hipFuncAttributeMaxDynamicSharedMemorySize, 65536);

    build_bpack_t<<<dim3(256, 2), 256, 0, stream>>>(caps_w, bpack);
    // wpack1 lives outside 'part', safe to build early; W2/bij aliased writes happen later.
    conv1_kernel_dep:;
    build_w2<<<96, 256, 0, stream>>>(Wr, (float*)W2, conv1_w, wpack1, bij);
    // NOTE: build_w2 writes W2/bij which alias 'part' — but capsconv writes part AFTER this,
    // so W2 must be rebuilt after part is dead. Move build_w2 after transpose_u instead:
    // (kept here only for wpack1; W2/bij rewritten below)
    conv1_mfma<<<720, 256, 0, stream>>>(x, wpack1, conv1_b, hTb);
    capsconv_mfma<<<408, 256, 61440, stream>>>(hTb, bpack, part);
    reduce_squash<<<1440, 192, 0, stream>>>(part, caps_b, u);
    transpose_u<<<dim3(288, 6), dim3(32, 32), 0, stream>>>(u, uTb);
    build_w2<<<96, 256, 0, stream>>>(Wr, (float*)W2, conv1_w, wpack1, bij);  // authoritative W2/bij

    for (int it = 0; it < 3; ++it){
        s_partial2<<<dim3(5, 72), 384, 0, stream>>>(W2, uTb, bij, part72, it == 0 ? 1 : 0);
        sred_vsq<<<180, 384, 0, stream>>>(part72, out);
        if (it < 2)
            p_uv<<<288, 320, 0, stream>>>(uTb, out, W2, bij);
    }
}

// Round 22
// 291.476 us; speedup vs baseline: 1.0197x; 1.0197x over previous
//
#include <hip/hip_runtime.h>
#include <hip/hip_bf16.h>

#define NB 180
typedef __attribute__((ext_vector_type(8))) short short8;
typedef __attribute__((ext_vector_type(4))) float f32x4;
typedef unsigned short ushort_t;

__device__ __forceinline__ void gload16(const void* src, void* lds_base){
    __builtin_amdgcn_global_load_lds(
        (const __attribute__((address_space(1))) unsigned int*)src,
        (__attribute__((address_space(3))) unsigned int*)lds_base, 16, 0, 0);
}

__device__ __forceinline__ ushort_t f2bu(float v){
    __hip_bfloat16 h = __float2bfloat16(v);
    return *(ushort_t*)&h;
}

__device__ __forceinline__ float bu2f(ushort_t v){
    union { unsigned int u; float f; } cv;
    cv.u = ((unsigned int)v) << 16;
    return cv.f;
}

// caps_w fp32 [oc][ic256*81] -> bpack bf16 [gk=kk*32+icg][oc][j], via LDS transpose.
__global__ __launch_bounds__(256) void build_bpack_t(const float* __restrict__ w,
                                                     __hip_bfloat16* __restrict__ bpack){
    __shared__ float ls[10368];                 // 128 ic x 81 kk
    int oc = blockIdx.x, ich = blockIdx.y, t = threadIdx.x;
    const float4* src = (const float4*)(w + (size_t)oc * 20736 + ich * 10368);
    for (int i = t; i < 2592; i += 256) ((float4*)ls)[i] = src[i];
    __syncthreads();
    for (int idx = t; idx < 10368; idx += 256){
        int j = idx & 7, icg = (idx >> 3) & 15, kk = idx >> 7;
        bpack[(size_t)(kk * 32 + ich * 16 + icg) * 2048 + oc * 8 + j] =
            __float2bfloat16(ls[(icg * 8 + j) * 81 + kk]);
    }
}

// conv1_w fp32 [oc256][81] -> wpack1 bf16 [(ks*4+g)][oc][j], k=ks*32+g*8+j, 0-pad k>=81.
__global__ __launch_bounds__(256) void build_wpack1(const float* __restrict__ w,
                                                    __hip_bfloat16* __restrict__ wpack1){
    int t = blockIdx.x * 256 + threadIdx.x;     // 24576
    int j = t & 7, oc = (t >> 3) & 255, gg = t >> 11;   // gg = ks*4+g
    int k = (gg >> 2) * 32 + (gg & 3) * 8 + j;
    float v = (k < 81) ? w[oc * 81 + k] : 0.f;
    wpack1[t] = __float2bfloat16(v);
}

// W_route fp32 [i1152][o10][d16][k8] -> W2 [o][ki=k*1152+i][d], via LDS; also zeroes bij.
// grid 96, block 256.
__global__ __launch_bounds__(256) void build_w2(const float* __restrict__ Wr, float* __restrict__ W2,
                                                float* __restrict__ bij){
    __shared__ float ls[15360];                 // 12 i x 1280
    int bid = blockIdx.x;
    int i0 = bid * 12, t = threadIdx.x;
    const float4* src = (const float4*)(Wr + (size_t)i0 * 1280);
    for (int w = t; w < 3840; w += 256) ((float4*)ls)[w] = src[w];
    if (t < 120) bij[bid * 120 + t] = 0.f;      // 96*120 = 11520
    __syncthreads();
    for (int idx = t; idx < 15360; idx += 256){
        int d = idx & 15, r = idx >> 4;
        int il = r % 12, ok = r / 12;           // ok = o*8+k
        int k = ok & 7, o = ok >> 3;
        W2[(size_t)o * 147456 + (size_t)(k * 1152 + i0 + il) * 16 + d] =
            ls[il * 1280 + o * 128 + d * 8 + k];
    }
}

// conv1 as MFMA implicit-GEMM (r13 verbatim): 112 px x 256 oc per block, K=96.
__global__ __launch_bounds__(256) void conv1_mfma(const float* __restrict__ x,
                                                  const __hip_bfloat16* __restrict__ wpack1,
                                                  const float* __restrict__ bias,
                                                  __hip_bfloat16* __restrict__ hT){
    __shared__ ushort_t xs[784];
    __shared__ ushort_t ktab[96];
    int bid = blockIdx.x;
    int b = bid >> 2, mc = bid & 3;
    int t = threadIdx.x, lane = t & 63, wn = t >> 6;
    int g = lane >> 4, lr = lane & 15;

    for (int i = t; i < 784; i += 256) xs[i] = f2bu(x[b * 784 + i]);
    if (t < 96) ktab[t] = (t < 81) ? (ushort_t)((t / 9) * 28 + (t % 9)) : (ushort_t)0;
    __syncthreads();

    int p0 = mc * 112;
    int pbm[7];
#pragma unroll
    for (int m = 0; m < 7; m++){
        int p = p0 + m * 16 + lr;
        p = p < 400 ? p : 399;
        pbm[m] = (p / 20) * 28 + (p % 20);
    }

    f32x4 acc[7][4];
#pragma unroll
    for (int m = 0; m < 7; m++)
#pragma unroll
        for (int n = 0; n < 4; n++) acc[m][n] = (f32x4){0.f, 0.f, 0.f, 0.f};

#pragma unroll
    for (int ks = 0; ks < 3; ks++){
        short8 ko = *(const short8*)&ktab[ks * 32 + g * 8];
        short8 bf[4];
#pragma unroll
        for (int n = 0; n < 4; n++)
            bf[n] = *(const short8*)(wpack1 + (size_t)(((ks * 4 + g) * 256) + wn * 64 + n * 16 + lr) * 8);
#pragma unroll
        for (int m = 0; m < 7; m++){
            short8 af;
#pragma unroll
            for (int e = 0; e < 8; e++)
                af[e] = (short)xs[pbm[m] + (int)(ushort_t)ko[e]];
#pragma unroll
            for (int n = 0; n < 4; n++)
                acc[m][n] = __builtin_amdgcn_mfma_f32_16x16x32_bf16(af, bf[n], acc[m][n], 0, 0, 0);
        }
    }

    float bv[4];
#pragma unroll
    for (int n = 0; n < 4; n++) bv[n] = bias[wn * 64 + n * 16 + lr];
#pragma unroll
    for (int m = 0; m < 7; m++){
#pragma unroll
        for (int rg = 0; rg < 4; rg++){
            int p = p0 + m * 16 + g * 4 + rg;
            if (p < 400){
#pragma unroll
                for (int n = 0; n < 4; n++){
                    float v = acc[m][n][rg] + bv[n];
                    v = v > 0.f ? v : 0.f;
                    hT[((size_t)b * 400 + p) * 256 + wn * 64 + n * 16 + lr] = __float2bfloat16(v);
                }
            }
        }
    }
}

// Implicit-GEMM capsconv — r19 verbatim (87.5 us): XCD remap + T5 setprio.
__global__ __launch_bounds__(256, 2) void capsconv_mfma(const __hip_bfloat16* __restrict__ hT,
                                                        const __hip_bfloat16* __restrict__ bpack,
                                                        float* __restrict__ part){
    extern __shared__ char smem[];               // 61440 B
    ushort_t* hsA = (ushort_t*)smem;

    int bid = blockIdx.x;
    int idx = (bid & 7) * 51 + (bid >> 3);
    if (idx >= 405) return;
    int mt = idx / 9, ky = idx - mt * 9;
    int b0 = mt * 4;
    int t = threadIdx.x, lane = t & 63, wn = t >> 6;
    int g = lane >> 4, lr = lane & 15;

    int pfm[9];
#pragma unroll
    for (int m = 0; m < 9; m++){
        int R = m * 16 + lr;
        int lb = R / 36, pos = R - lb * 36;
        int oy = pos / 6, ox = pos - oy * 6;
        int yy = lb * 6 + oy;
        pfm[m] = ((yy * 20 + 2 * ox) << 8) | (ox + 6 * yy);
    }
    int gbase = g * 2048 + wn * 512 + lr * 8;    // B lane offset (bf16 elems)

    auto stageA = [&](int a){
#pragma unroll
        for (int rnd = 0; rnd < 15; rnd++){
            int L = rnd * 256 + t;               // granule 0..3839
            int p = L >> 3, sg = L & 7;
            int yy = p / 20, xx = p - yy * 20;
            int lb = yy / 6;
            int y = ky + 2 * (yy - lb * 6);
            int f = ((xx >> 1) + 6 * yy) & 7;
            const __hip_bfloat16* src = hT + ((size_t)(((b0 + lb) * 20 + y) * 20 + xx) * 256
                                             + a * 64 + 8 * (sg ^ f));
            gload16(src, hsA + (size_t)(rnd * 256 + (t & ~63)) * 8);
        }
    };

    f32x4 acc[9][4];
#pragma unroll
    for (int m = 0; m < 9; m++)
#pragma unroll
        for (int n = 0; n < 4; n++) acc[m][n] = (f32x4){0.f, 0.f, 0.f, 0.f};

    stageA(0);
    __syncthreads();

    for (int a = 0; a < 4; a++){
#pragma unroll 2
        for (int r = 0; r < 18; r++){
            int kx = r >> 1, ics = r & 1;
            int ksg = (ky * 9 + kx) * 8 + 2 * a + ics;   // wave-uniform
            const __hip_bfloat16* bstep = bpack + (size_t)ksg * 8192 + gbase;
            short8 bf[4];
#pragma unroll
            for (int n = 0; n < 4; n++)
                bf[n] = *(const short8*)(bstep + n * 128);
            int jj = ics * 4 + g;
            __builtin_amdgcn_s_setprio(1);       // T5
#pragma unroll
            for (int m = 0; m < 9; m++){
                int pf = pfm[m];
                int p = (pf >> 8) + kx;
                int f = ((pf & 255) + (kx >> 1)) & 7;
                short8 af = *(const short8*)(hsA + (size_t)(p * 8 + (jj ^ f)) * 8);
#pragma unroll
                for (int n = 0; n < 4; n++)
                    acc[m][n] = __builtin_amdgcn_mfma_f32_16x16x32_bf16(af, bf[n], acc[m][n], 0, 0, 0);
            }
            __builtin_amdgcn_s_setprio(0);
        }
        if (a < 3){
            __syncthreads();     // all waves done reading chunk a
            stageA(a + 1);
            __syncthreads();     // drains gload16s + visibility
        }
    }

    // Epilogue: per-lb LDS transpose tile tl[pos 36][oc 260], conflict-free.
    float* tl = (float*)smem;
    size_t pbase = ((size_t)ky * 180 + b0) * 9216;
    for (int lb = 0; lb < 4; lb++){
        int rlo = lb * 36;
        __syncthreads();
#pragma unroll
        for (int m = 0; m < 9; m++){
#pragma unroll
            for (int n = 0; n < 4; n++){
                int oc = wn * 64 + n * 16 + lr;
#pragma unroll
                for (int rg = 0; rg < 4; rg++){
                    int row = m * 16 + g * 4 + rg;
                    if (row >= rlo && row < rlo + 36)
                        tl[(row - rlo) * 260 + oc] = acc[m][n][rg];
                }
            }
        }
        __syncthreads();
#pragma unroll
        for (int j = 0; j < 9; j++){
            int pos = j * 4;
            float4 vv;
            vv.x = tl[(pos    ) * 260 + t];
            vv.y = tl[(pos + 1) * 260 + t];
            vv.z = tl[(pos + 2) * 260 + t];
            vv.w = tl[(pos + 3) * 260 + t];
            *(float4*)&part[pbase + (size_t)lb * 9216 + t * 36 + pos] = vv;
        }
    }
}

// reduce 9 ky-partials + bias, squash over each (b,k) 1152-block, COALESCED write to u[b][ki].
__global__ __launch_bounds__(192) void reduce_squash(const float* __restrict__ part,
                                                     const float* __restrict__ caps_b,
                                                     float* __restrict__ u){
    __shared__ float red[3];
    int bk = blockIdx.x;
    int b = bk >> 3, k = bk & 7;
    int t = threadIdx.x;
    size_t base = (size_t)k * 1152;
    float vals[6];
    float ssq = 0.f;
#pragma unroll
    for (int j = 0; j < 6; j++){
        int i = t + j * 192;
        int oc = k * 32 + i / 36;
        float v = caps_b[oc];
#pragma unroll
        for (int kyi = 0; kyi < 9; kyi++)
            v += part[(size_t)(kyi * 180 + b) * 9216 + base + i];
        vals[j] = v; ssq += v * v;
    }
#pragma unroll
    for (int off = 32; off; off >>= 1) ssq += __shfl_down(ssq, off, 64);
    if ((t & 63) == 0) red[t >> 6] = ssq;
    __syncthreads();
    float tot = red[0] + red[1] + red[2];
    float scale = 1.f / (sqrtf(tot) + tot);
#pragma unroll
    for (int j = 0; j < 6; j++)
        u[(size_t)b * 9216 + base + t + j * 192] = vals[j] * scale;
}

// u [b][ki=9216] fp32 -> uTb [ki][b=180] bf16, coalesced 32x32 tiles.
__global__ __launch_bounds__(1024) void transpose_u(const float* __restrict__ u, ushort_t* __restrict__ uTb){
    __shared__ float tile[32][33];
    int ki0 = blockIdx.x * 32, b0 = blockIdx.y * 32;
    int tx = threadIdx.x, ty = threadIdx.y;
    int b = b0 + ty;
    if (b < NB) tile[ty][tx] = u[(size_t)b * 9216 + ki0 + tx];
    __syncthreads();
    int bw = b0 + tx;
    if (bw < NB) uTb[(size_t)(ki0 + ty) * NB + bw] = f2bu(tile[tx][ty]);
}

// split-K s-partials, softmax fused in; paired-o blocks; uT in bf16. (r20 verbatim)
__global__ __launch_bounds__(384) void s_partial2(const float* __restrict__ W2, const ushort_t* __restrict__ uTb,
                                                  const float* __restrict__ bij, float* __restrict__ part72,
                                                  int first){
    __shared__ float ws2[2][2048];
    __shared__ float cs[2][128];
    int op = blockIdx.x, kc = blockIdx.y, t = threadIdx.x;
    int grp = t / 192, tg = t - grp * 192;
    int o = op * 2 + grp;
    const float4* src = (const float4*)(W2 + (size_t)o * 147456 + (size_t)kc * 2048);
    for (int w = tg; w < 512; w += 192) ((float4*)ws2[grp])[w] = src[w];
    if (tg < 128){
        if (first){
            cs[grp][tg] = 0.1f;
        } else {
            int ki = kc * 128 + tg;
            int i = ki - (ki / 1152) * 1152;
            const float* bp = bij + (size_t)i * 10;
            float v[10]; float mx = -1e30f;
#pragma unroll
            for (int q = 0; q < 10; q++){ v[q] = bp[q]; mx = fmaxf(mx, v[q]); }
            float sum = 0.f;
#pragma unroll
            for (int q = 0; q < 10; q++){ v[q] = __expf(v[q] - mx); sum += v[q]; }
            cs[grp][tg] = v[o] / sum;
        }
    }
    __syncthreads();
    if (tg < NB){
        f32x4 a0 = {0,0,0,0}, a1 = {0,0,0,0}, a2 = {0,0,0,0}, a3 = {0,0,0,0};
        const ushort_t* up = uTb + (size_t)kc * 128 * NB + tg;
        const float* w2g = ws2[grp];
        const float* csg = cs[grp];
#pragma unroll 4
        for (int j = 0; j < 128; j++){
            float tmp = bu2f(up[j * NB]) * csg[j];
            const f32x4* wp = (const f32x4*)(w2g + j * 16);
            a0 += tmp * wp[0]; a1 += tmp * wp[1]; a2 += tmp * wp[2]; a3 += tmp * wp[3];
        }
        f32x4* pp = (f32x4*)(part72 + ((size_t)kc * NB + tg) * 160 + o * 16);
        pp[0] = a0; pp[1] = a1; pp[2] = a2; pp[3] = a3;
    }
}

// fused: s[b][od] = sum_kc part72[kc][b][od] ; v = s / (sqrt(msq)+msq), msq over o. (r20 verbatim)
__global__ __launch_bounds__(192) void sred_vsq(const float* __restrict__ part72, float* __restrict__ v){
    __shared__ float sv[160];
    __shared__ float sc[16];
    int b = blockIdx.x, t = threadIdx.x;
    float s = 0.f;
    if (t < 160){
        const float* pp = part72 + (size_t)b * 160 + t;
        for (int kc = 0; kc < 72; kc++)
            s += pp[(size_t)kc * NB * 160];
        sv[t] = s;
    }
    __syncthreads();
    if (t < 16){
        float m = 0.f;
#pragma unroll
        for (int o = 0; o < 10; o++){ float x = sv[o * 16 + t]; m += x * x; }
        sc[t] = 1.f / (sqrtf(m) + m);
    }
    __syncthreads();
    if (t < 160) v[b * 160 + t] = s * sc[t & 15];
}

// fused p_gemm + uv_contract: P-tile in regs, dot with W2, atomicAdd into bij. (r20 verbatim)
__global__ __launch_bounds__(320) void p_uv(const ushort_t* __restrict__ uTb, const float* __restrict__ v,
                                            const float* __restrict__ W2, float* __restrict__ bij){
    __shared__ float vs[60 * 160];
    int t = threadIdx.x;
    int o = t % 10, kil = t / 10;
    int ki = blockIdx.x * 32 + kil;
    float acc[16];
#pragma unroll
    for (int d = 0; d < 16; d++) acc[d] = 0.f;
    const ushort_t* up = uTb + (size_t)ki * NB;
    for (int b0 = 0; b0 < NB; b0 += 60){
        __syncthreads();
        for (int j = t; j < 9600; j += 320) vs[j] = v[b0 * 160 + j];
        __syncthreads();
        for (int b = 0; b < 60; b++){
            float uv = bu2f(up[b0 + b]);
            const float* vp = &vs[b * 160 + o * 16];
#pragma unroll
            for (int d = 0; d < 16; d++) acc[d] += uv * vp[d];
        }
    }
    const float4* wp = (const float4*)(W2 + (size_t)o * 147456 + (size_t)ki * 16);
    float dot = 0.f;
#pragma unroll
    for (int q = 0; q < 4; q++){
        float4 a = wp[q];
        dot += a.x * acc[q*4] + a.y * acc[q*4+1] + a.z * acc[q*4+2] + a.w * acc[q*4+3];
    }
    int i = ki % 1152;
    atomicAdd(&bij[i * 10 + o], dot * (1.0f / 180.0f));
}

extern "C" void kernel_launch(void* const* d_in, const int* in_sizes, int n_in,
                              void* d_out, int out_size, void* d_ws, size_t ws_size,
                              hipStream_t stream){
    const float* x       = (const float*)d_in[0];
    const float* conv1_w = (const float*)d_in[1];
    const float* conv1_b = (const float*)d_in[2];
    const float* caps_w  = (const float*)d_in[3];
    const float* caps_b  = (const float*)d_in[4];
    const float* Wr      = (const float*)d_in[5];
    float* out = (float*)d_out;

    char* wsb = (char*)d_ws;
    __hip_bfloat16* hTb   = (__hip_bfloat16*)wsb;                  // 36,864,000 B
    __hip_bfloat16* bpack = (__hip_bfloat16*)(wsb + 36864000);     // 10,616,832 B
    float* part = (float*)(wsb + 36864000 + 10616832);             // 59,719,680 B
    float* u    = part + 14929920;                                 //  6,635,520 B
    ushort_t* uTb = (ushort_t*)(u + 1658880);                      //  3,317,760 B (bf16)
    __hip_bfloat16* wpack1 = (__hip_bfloat16*)((char*)uTb + 3317760); // 49,152 B

    // routing scratch aliases 'part' (dead after reduce_squash + transpose_u)
    float* W2     = part;                     // 1,474,560 f
    float* part72 = W2 + 1474560;             // 2,073,600 f
    float* bij    = part72 + 2073600;         //    11,520 f

    hipFuncSetAttribute((const void*)capsconv_mfma,
                        hipFuncAttributeMaxDynamicSharedMemorySize, 65536);

    build_bpack_t<<<dim3(256, 2), 256, 0, stream>>>(caps_w, bpack);
    build_wpack1<<<96, 256, 0, stream>>>(conv1_w, wpack1);
    conv1_mfma<<<720, 256, 0, stream>>>(x, wpack1, conv1_b, hTb);
    capsconv_mfma<<<408, 256, 61440, stream>>>(hTb, bpack, part);
    reduce_squash<<<1440, 192, 0, stream>>>(part, caps_b, u);
    transpose_u<<<dim3(288, 6), dim3(32, 32), 0, stream>>>(u, uTb);
    build_w2<<<96, 256, 0, stream>>>(Wr, W2, bij);   // after part is dead; also zeroes bij

    for (int it = 0; it < 3; ++it){
        s_partial2<<<dim3(5, 72), 384, 0, stream>>>(W2, uTb, bij, part72, it == 0 ? 1 : 0);
        sred_vsq<<<180, 192, 0, stream>>>(part72, out);
        if (it < 2)
            p_uv<<<288, 320, 0, stream>>>(uTb, out, W2, bij);
    }
}

// Round 23
// 279.974 us; speedup vs baseline: 1.0616x; 1.0411x over previous
//
#include <hip/hip_runtime.h>
#include <hip/hip_bf16.h>

#define NB 180
typedef __attribute__((ext_vector_type(8))) short short8;
typedef __attribute__((ext_vector_type(4))) float f32x4;
typedef unsigned short ushort_t;
typedef __attribute__((ext_vector_type(4))) ushort_t ushort4_t;

__device__ __forceinline__ void gload16(const void* src, void* lds_base){
    __builtin_amdgcn_global_load_lds(
        (const __attribute__((address_space(1))) unsigned int*)src,
        (__attribute__((address_space(3))) unsigned int*)lds_base, 16, 0, 0);
}

__device__ __forceinline__ ushort_t f2bu(float v){
    __hip_bfloat16 h = __float2bfloat16(v);
    return *(ushort_t*)&h;
}

__device__ __forceinline__ float bu2f(ushort_t v){
    union { unsigned int u; float f; } cv;
    cv.u = ((unsigned int)v) << 16;
    return cv.f;
}

// caps_w fp32 [oc][ic256*81] -> bpack bf16 [gk=kk*32+icg][oc][j], via LDS transpose.
__global__ __launch_bounds__(256) void build_bpack_t(const float* __restrict__ w,
                                                     __hip_bfloat16* __restrict__ bpack){
    __shared__ float ls[10368];                 // 128 ic x 81 kk
    int oc = blockIdx.x, ich = blockIdx.y, t = threadIdx.x;
    const float4* src = (const float4*)(w + (size_t)oc * 20736 + ich * 10368);
    for (int i = t; i < 2592; i += 256) ((float4*)ls)[i] = src[i];
    __syncthreads();
    for (int idx = t; idx < 10368; idx += 256){
        int j = idx & 7, icg = (idx >> 3) & 15, kk = idx >> 7;
        bpack[(size_t)(kk * 32 + ich * 16 + icg) * 2048 + oc * 8 + j] =
            __float2bfloat16(ls[(icg * 8 + j) * 81 + kk]);
    }
}

// conv1_w fp32 [oc256][81] -> wpack1 bf16 [(ks*4+g)][oc][j], k=ks*32+g*8+j, 0-pad k>=81.
__global__ __launch_bounds__(256) void build_wpack1(const float* __restrict__ w,
                                                    __hip_bfloat16* __restrict__ wpack1){
    int t = blockIdx.x * 256 + threadIdx.x;     // 24576
    int j = t & 7, oc = (t >> 3) & 255, gg = t >> 11;   // gg = ks*4+g
    int k = (gg >> 2) * 32 + (gg & 3) * 8 + j;
    float v = (k < 81) ? w[oc * 81 + k] : 0.f;
    wpack1[t] = __float2bfloat16(v);
}

// W_route fp32 [i1152][o10][d16][k8] -> W2 [o][ki=k*1152+i][d], via LDS; also zeroes bij.
__global__ __launch_bounds__(256) void build_w2(const float* __restrict__ Wr, float* __restrict__ W2,
                                                float* __restrict__ bij){
    __shared__ float ls[15360];                 // 12 i x 1280
    int bid = blockIdx.x;
    int i0 = bid * 12, t = threadIdx.x;
    const float4* src = (const float4*)(Wr + (size_t)i0 * 1280);
    for (int w = t; w < 3840; w += 256) ((float4*)ls)[w] = src[w];
    if (t < 120) bij[bid * 120 + t] = 0.f;      // 96*120 = 11520
    __syncthreads();
    for (int idx = t; idx < 15360; idx += 256){
        int d = idx & 15, r = idx >> 4;
        int il = r % 12, ok = r / 12;           // ok = o*8+k
        int k = ok & 7, o = ok >> 3;
        W2[(size_t)o * 147456 + (size_t)(k * 1152 + i0 + il) * 16 + d] =
            ls[il * 1280 + o * 128 + d * 8 + k];
    }
}

// conv1 as MFMA implicit-GEMM (r13 verbatim): 112 px x 256 oc per block, K=96.
__global__ __launch_bounds__(256) void conv1_mfma(const float* __restrict__ x,
                                                  const __hip_bfloat16* __restrict__ wpack1,
                                                  const float* __restrict__ bias,
                                                  __hip_bfloat16* __restrict__ hT){
    __shared__ ushort_t xs[784];
    __shared__ ushort_t ktab[96];
    int bid = blockIdx.x;
    int b = bid >> 2, mc = bid & 3;
    int t = threadIdx.x, lane = t & 63, wn = t >> 6;
    int g = lane >> 4, lr = lane & 15;

    for (int i = t; i < 784; i += 256) xs[i] = f2bu(x[b * 784 + i]);
    if (t < 96) ktab[t] = (t < 81) ? (ushort_t)((t / 9) * 28 + (t % 9)) : (ushort_t)0;
    __syncthreads();

    int p0 = mc * 112;
    int pbm[7];
#pragma unroll
    for (int m = 0; m < 7; m++){
        int p = p0 + m * 16 + lr;
        p = p < 400 ? p : 399;
        pbm[m] = (p / 20) * 28 + (p % 20);
    }

    f32x4 acc[7][4];
#pragma unroll
    for (int m = 0; m < 7; m++)
#pragma unroll
        for (int n = 0; n < 4; n++) acc[m][n] = (f32x4){0.f, 0.f, 0.f, 0.f};

#pragma unroll
    for (int ks = 0; ks < 3; ks++){
        short8 ko = *(const short8*)&ktab[ks * 32 + g * 8];
        short8 bf[4];
#pragma unroll
        for (int n = 0; n < 4; n++)
            bf[n] = *(const short8*)(wpack1 + (size_t)(((ks * 4 + g) * 256) + wn * 64 + n * 16 + lr) * 8);
#pragma unroll
        for (int m = 0; m < 7; m++){
            short8 af;
#pragma unroll
            for (int e = 0; e < 8; e++)
                af[e] = (short)xs[pbm[m] + (int)(ushort_t)ko[e]];
#pragma unroll
            for (int n = 0; n < 4; n++)
                acc[m][n] = __builtin_amdgcn_mfma_f32_16x16x32_bf16(af, bf[n], acc[m][n], 0, 0, 0);
        }
    }

    float bv[4];
#pragma unroll
    for (int n = 0; n < 4; n++) bv[n] = bias[wn * 64 + n * 16 + lr];
#pragma unroll
    for (int m = 0; m < 7; m++){
#pragma unroll
        for (int rg = 0; rg < 4; rg++){
            int p = p0 + m * 16 + g * 4 + rg;
            if (p < 400){
#pragma unroll
                for (int n = 0; n < 4; n++){
                    float v = acc[m][n][rg] + bv[n];
                    v = v > 0.f ? v : 0.f;
                    hT[((size_t)b * 400 + p) * 256 + wn * 64 + n * 16 + lr] = __float2bfloat16(v);
                }
            }
        }
    }
}

// Implicit-GEMM capsconv — r19 structure (XCD remap + T5 setprio); part now bf16.
__global__ __launch_bounds__(256, 2) void capsconv_mfma(const __hip_bfloat16* __restrict__ hT,
                                                        const __hip_bfloat16* __restrict__ bpack,
                                                        ushort_t* __restrict__ partb){
    extern __shared__ char smem[];               // 61440 B
    ushort_t* hsA = (ushort_t*)smem;

    int bid = blockIdx.x;
    int idx = (bid & 7) * 51 + (bid >> 3);
    if (idx >= 405) return;
    int mt = idx / 9, ky = idx - mt * 9;
    int b0 = mt * 4;
    int t = threadIdx.x, lane = t & 63, wn = t >> 6;
    int g = lane >> 4, lr = lane & 15;

    int pfm[9];
#pragma unroll
    for (int m = 0; m < 9; m++){
        int R = m * 16 + lr;
        int lb = R / 36, pos = R - lb * 36;
        int oy = pos / 6, ox = pos - oy * 6;
        int yy = lb * 6 + oy;
        pfm[m] = ((yy * 20 + 2 * ox) << 8) | (ox + 6 * yy);
    }
    int gbase = g * 2048 + wn * 512 + lr * 8;    // B lane offset (bf16 elems)

    auto stageA = [&](int a){
#pragma unroll
        for (int rnd = 0; rnd < 15; rnd++){
            int L = rnd * 256 + t;               // granule 0..3839
            int p = L >> 3, sg = L & 7;
            int yy = p / 20, xx = p - yy * 20;
            int lb = yy / 6;
            int y = ky + 2 * (yy - lb * 6);
            int f = ((xx >> 1) + 6 * yy) & 7;
            const __hip_bfloat16* src = hT + ((size_t)(((b0 + lb) * 20 + y) * 20 + xx) * 256
                                             + a * 64 + 8 * (sg ^ f));
            gload16(src, hsA + (size_t)(rnd * 256 + (t & ~63)) * 8);
        }
    };

    f32x4 acc[9][4];
#pragma unroll
    for (int m = 0; m < 9; m++)
#pragma unroll
        for (int n = 0; n < 4; n++) acc[m][n] = (f32x4){0.f, 0.f, 0.f, 0.f};

    stageA(0);
    __syncthreads();

    for (int a = 0; a < 4; a++){
#pragma unroll 2
        for (int r = 0; r < 18; r++){
            int kx = r >> 1, ics = r & 1;
            int ksg = (ky * 9 + kx) * 8 + 2 * a + ics;   // wave-uniform
            const __hip_bfloat16* bstep = bpack + (size_t)ksg * 8192 + gbase;
            short8 bf[4];
#pragma unroll
            for (int n = 0; n < 4; n++)
                bf[n] = *(const short8*)(bstep + n * 128);
            int jj = ics * 4 + g;
            __builtin_amdgcn_s_setprio(1);       // T5
#pragma unroll
            for (int m = 0; m < 9; m++){
                int pf = pfm[m];
                int p = (pf >> 8) + kx;
                int f = ((pf & 255) + (kx >> 1)) & 7;
                short8 af = *(const short8*)(hsA + (size_t)(p * 8 + (jj ^ f)) * 8);
#pragma unroll
                for (int n = 0; n < 4; n++)
                    acc[m][n] = __builtin_amdgcn_mfma_f32_16x16x32_bf16(af, bf[n], acc[m][n], 0, 0, 0);
            }
            __builtin_amdgcn_s_setprio(0);
        }
        if (a < 3){
            __syncthreads();     // all waves done reading chunk a
            stageA(a + 1);
            __syncthreads();     // drains gload16s + visibility
        }
    }

    // Epilogue: per-lb LDS transpose tile tl[pos 36][oc 260]; bf16 stores (8B ushort4).
    float* tl = (float*)smem;
    size_t pbase = ((size_t)ky * 180 + b0) * 9216;
    for (int lb = 0; lb < 4; lb++){
        int rlo = lb * 36;
        __syncthreads();
#pragma unroll
        for (int m = 0; m < 9; m++){
#pragma unroll
            for (int n = 0; n < 4; n++){
                int oc = wn * 64 + n * 16 + lr;
#pragma unroll
                for (int rg = 0; rg < 4; rg++){
                    int row = m * 16 + g * 4 + rg;
                    if (row >= rlo && row < rlo + 36)
                        tl[(row - rlo) * 260 + oc] = acc[m][n][rg];
                }
            }
        }
        __syncthreads();
#pragma unroll
        for (int j = 0; j < 9; j++){
            int pos = j * 4;
            ushort4_t sv;
            sv.x = f2bu(tl[(pos    ) * 260 + t]);
            sv.y = f2bu(tl[(pos + 1) * 260 + t]);
            sv.z = f2bu(tl[(pos + 2) * 260 + t]);
            sv.w = f2bu(tl[(pos + 3) * 260 + t]);
            *(ushort4_t*)&partb[pbase + (size_t)lb * 9216 + t * 36 + pos] = sv;
        }
    }
}

// reduce 9 bf16 ky-partials + bias, squash over each (b,k) 1152-block, COALESCED write to u[b][ki].
__global__ __launch_bounds__(192) void reduce_squash(const ushort_t* __restrict__ partb,
                                                     const float* __restrict__ caps_b,
                                                     float* __restrict__ u){
    __shared__ float red[3];
    int bk = blockIdx.x;
    int b = bk >> 3, k = bk & 7;
    int t = threadIdx.x;
    size_t base = (size_t)k * 1152;
    float vals[6];
    float ssq = 0.f;
#pragma unroll
    for (int j = 0; j < 6; j++){
        int i = t + j * 192;
        int oc = k * 32 + i / 36;
        float v = caps_b[oc];
#pragma unroll
        for (int kyi = 0; kyi < 9; kyi++)
            v += bu2f(partb[(size_t)(kyi * 180 + b) * 9216 + base + i]);
        vals[j] = v; ssq += v * v;
    }
#pragma unroll
    for (int off = 32; off; off >>= 1) ssq += __shfl_down(ssq, off, 64);
    if ((t & 63) == 0) red[t >> 6] = ssq;
    __syncthreads();
    float tot = red[0] + red[1] + red[2];
    float scale = 1.f / (sqrtf(tot) + tot);
#pragma unroll
    for (int j = 0; j < 6; j++)
        u[(size_t)b * 9216 + base + t + j * 192] = vals[j] * scale;
}

// u [b][ki=9216] fp32 -> uTb [ki][b=180] bf16, coalesced 32x32 tiles.
__global__ __launch_bounds__(1024) void transpose_u(const float* __restrict__ u, ushort_t* __restrict__ uTb){
    __shared__ float tile[32][33];
    int ki0 = blockIdx.x * 32, b0 = blockIdx.y * 32;
    int tx = threadIdx.x, ty = threadIdx.y;
    int b = b0 + ty;
    if (b < NB) tile[ty][tx] = u[(size_t)b * 9216 + ki0 + tx];
    __syncthreads();
    int bw = b0 + tx;
    if (bw < NB) uTb[(size_t)(ki0 + ty) * NB + bw] = f2bu(tile[tx][ty]);
}

// split-K s-partials, softmax fused in; paired-o blocks; uT in bf16. (r22 verbatim)
__global__ __launch_bounds__(384) void s_partial2(const float* __restrict__ W2, const ushort_t* __restrict__ uTb,
                                                  const float* __restrict__ bij, float* __restrict__ part72,
                                                  int first){
    __shared__ float ws2[2][2048];
    __shared__ float cs[2][128];
    int op = blockIdx.x, kc = blockIdx.y, t = threadIdx.x;
    int grp = t / 192, tg = t - grp * 192;
    int o = op * 2 + grp;
    const float4* src = (const float4*)(W2 + (size_t)o * 147456 + (size_t)kc * 2048);
    for (int w = tg; w < 512; w += 192) ((float4*)ws2[grp])[w] = src[w];
    if (tg < 128){
        if (first){
            cs[grp][tg] = 0.1f;
        } else {
            int ki = kc * 128 + tg;
            int i = ki - (ki / 1152) * 1152;
            const float* bp = bij + (size_t)i * 10;
            float v[10]; float mx = -1e30f;
#pragma unroll
            for (int q = 0; q < 10; q++){ v[q] = bp[q]; mx = fmaxf(mx, v[q]); }
            float sum = 0.f;
#pragma unroll
            for (int q = 0; q < 10; q++){ v[q] = __expf(v[q] - mx); sum += v[q]; }
            cs[grp][tg] = v[o] / sum;
        }
    }
    __syncthreads();
    if (tg < NB){
        f32x4 a0 = {0,0,0,0}, a1 = {0,0,0,0}, a2 = {0,0,0,0}, a3 = {0,0,0,0};
        const ushort_t* up = uTb + (size_t)kc * 128 * NB + tg;
        const float* w2g = ws2[grp];
        const float* csg = cs[grp];
#pragma unroll 4
        for (int j = 0; j < 128; j++){
            float tmp = bu2f(up[j * NB]) * csg[j];
            const f32x4* wp = (const f32x4*)(w2g + j * 16);
            a0 += tmp * wp[0]; a1 += tmp * wp[1]; a2 += tmp * wp[2]; a3 += tmp * wp[3];
        }
        f32x4* pp = (f32x4*)(part72 + ((size_t)kc * NB + tg) * 160 + o * 16);
        pp[0] = a0; pp[1] = a1; pp[2] = a2; pp[3] = a3;
    }
}

// fused: s[b][od] = sum_kc part72[kc][b][od] ; v = s / (sqrt(msq)+msq), msq over o. (r22 verbatim)
__global__ __launch_bounds__(192) void sred_vsq(const float* __restrict__ part72, float* __restrict__ v){
    __shared__ float sv[160];
    __shared__ float sc[16];
    int b = blockIdx.x, t = threadIdx.x;
    float s = 0.f;
    if (t < 160){
        const float* pp = part72 + (size_t)b * 160 + t;
        for (int kc = 0; kc < 72; kc++)
            s += pp[(size_t)kc * NB * 160];
        sv[t] = s;
    }
    __syncthreads();
    if (t < 16){
        float m = 0.f;
#pragma unroll
        for (int o = 0; o < 10; o++){ float x = sv[o * 16 + t]; m += x * x; }
        sc[t] = 1.f / (sqrtf(m) + m);
    }
    __syncthreads();
    if (t < 160) v[b * 160 + t] = s * sc[t & 15];
}

// fused p_gemm + uv_contract: P-tile in regs, dot with W2, atomicAdd into bij. (r22 verbatim)
__global__ __launch_bounds__(320) void p_uv(const ushort_t* __restrict__ uTb, const float* __restrict__ v,
                                            const float* __restrict__ W2, float* __restrict__ bij){
    __shared__ float vs[60 * 160];
    int t = threadIdx.x;
    int o = t % 10, kil = t / 10;
    int ki = blockIdx.x * 32 + kil;
    float acc[16];
#pragma unroll
    for (int d = 0; d < 16; d++) acc[d] = 0.f;
    const ushort_t* up = uTb + (size_t)ki * NB;
    for (int b0 = 0; b0 < NB; b0 += 60){
        __syncthreads();
        for (int j = t; j < 9600; j += 320) vs[j] = v[b0 * 160 + j];
        __syncthreads();
        for (int b = 0; b < 60; b++){
            float uv = bu2f(up[b0 + b]);
            const float* vp = &vs[b * 160 + o * 16];
#pragma unroll
            for (int d = 0; d < 16; d++) acc[d] += uv * vp[d];
        }
    }
    const float4* wp = (const float4*)(W2 + (size_t)o * 147456 + (size_t)ki * 16);
    float dot = 0.f;
#pragma unroll
    for (int q = 0; q < 4; q++){
        float4 a = wp[q];
        dot += a.x * acc[q*4] + a.y * acc[q*4+1] + a.z * acc[q*4+2] + a.w * acc[q*4+3];
    }
    int i = ki % 1152;
    atomicAdd(&bij[i * 10 + o], dot * (1.0f / 180.0f));
}

extern "C" void kernel_launch(void* const* d_in, const int* in_sizes, int n_in,
                              void* d_out, int out_size, void* d_ws, size_t ws_size,
                              hipStream_t stream){
    const float* x       = (const float*)d_in[0];
    const float* conv1_w = (const float*)d_in[1];
    const float* conv1_b = (const float*)d_in[2];
    const float* caps_w  = (const float*)d_in[3];
    const float* caps_b  = (const float*)d_in[4];
    const float* Wr      = (const float*)d_in[5];
    float* out = (float*)d_out;

    char* wsb = (char*)d_ws;
    __hip_bfloat16* hTb   = (__hip_bfloat16*)wsb;                  // 36,864,000 B
    __hip_bfloat16* bpack = (__hip_bfloat16*)(wsb + 36864000);     // 10,616,832 B
    ushort_t* partb = (ushort_t*)(wsb + 36864000 + 10616832);      // 29,859,840 B (bf16)
    float* u    = (float*)((char*)partb + 29859840);               //  6,635,520 B
    ushort_t* uTb = (ushort_t*)(u + 1658880);                      //  3,317,760 B (bf16)
    __hip_bfloat16* wpack1 = (__hip_bfloat16*)((char*)uTb + 3317760); // 49,152 B

    // routing scratch aliases 'partb' region (dead after reduce_squash + transpose_u)
    float* W2     = (float*)partb;            // 1,474,560 f (5.9 MB)
    float* part72 = W2 + 1474560;             // 2,073,600 f (8.3 MB)
    float* bij    = part72 + 2073600;         //    11,520 f   (total 14.2 MB < 29.9 MB)

    hipFuncSetAttribute((const void*)capsconv_mfma,
                        hipFuncAttributeMaxDynamicSharedMemorySize, 65536);

    build_bpack_t<<<dim3(256, 2), 256, 0, stream>>>(caps_w, bpack);
    build_wpack1<<<96, 256, 0, stream>>>(conv1_w, wpack1);
    conv1_mfma<<<720, 256, 0, stream>>>(x, wpack1, conv1_b, hTb);
    capsconv_mfma<<<408, 256, 61440, stream>>>(hTb, bpack, partb);
    reduce_squash<<<1440, 192, 0, stream>>>(partb, caps_b, u);
    transpose_u<<<dim3(288, 6), dim3(32, 32), 0, stream>>>(u, uTb);
    build_w2<<<96, 256, 0, stream>>>(Wr, W2, bij);   // after partb is dead; also zeroes bij

    for (int it = 0; it < 3; ++it){
        s_partial2<<<dim3(5, 72), 384, 0, stream>>>(W2, uTb, bij, part72, it == 0 ? 1 : 0);
        sred_vsq<<<180, 192, 0, stream>>>(part72, out);
        if (it < 2)
            p_uv<<<288, 320, 0, stream>>>(uTb, out, W2, bij);
    }
}

// Round 24
// 277.356 us; speedup vs baseline: 1.0716x; 1.0094x over previous
//
#include <hip/hip_runtime.h>
#include <hip/hip_bf16.h>

#define NB 180
typedef __attribute__((ext_vector_type(8))) short short8;
typedef __attribute__((ext_vector_type(4))) float f32x4;
typedef unsigned short ushort_t;
typedef __attribute__((ext_vector_type(4))) ushort_t ushort4_t;

__device__ __forceinline__ void gload16(const void* src, void* lds_base){
    __builtin_amdgcn_global_load_lds(
        (const __attribute__((address_space(1))) unsigned int*)src,
        (__attribute__((address_space(3))) unsigned int*)lds_base, 16, 0, 0);
}

__device__ __forceinline__ ushort_t f2bu(float v){
    __hip_bfloat16 h = __float2bfloat16(v);
    return *(ushort_t*)&h;
}

__device__ __forceinline__ float bu2f(ushort_t v){
    union { unsigned int u; float f; } cv;
    cv.u = ((unsigned int)v) << 16;
    return cv.f;
}

// caps_w fp32 [oc][ic256*81] -> bpack bf16 [gk=kk*32+icg][oc][j], via LDS transpose.
// ALSO: blocks (y==0, x<96) build wpack1 (conv1 weights, independent data).
__global__ __launch_bounds__(256) void build_bpack_t(const float* __restrict__ w,
                                                     __hip_bfloat16* __restrict__ bpack,
                                                     const float* __restrict__ cw1,
                                                     __hip_bfloat16* __restrict__ wpack1){
    __shared__ float ls[10368];                 // 128 ic x 81 kk
    int oc = blockIdx.x, ich = blockIdx.y, t = threadIdx.x;
    if (ich == 0 && oc < 96){
        int e = oc * 256 + t;                   // 24576 total
        int j = e & 7, oc1 = (e >> 3) & 255, gg = e >> 11;   // gg = ks*4+g
        int k = (gg >> 2) * 32 + (gg & 3) * 8 + j;
        float v = (k < 81) ? cw1[oc1 * 81 + k] : 0.f;
        wpack1[e] = __float2bfloat16(v);
    }
    const float4* src = (const float4*)(w + (size_t)oc * 20736 + ich * 10368);
    for (int i = t; i < 2592; i += 256) ((float4*)ls)[i] = src[i];
    __syncthreads();
    for (int idx = t; idx < 10368; idx += 256){
        int j = idx & 7, icg = (idx >> 3) & 15, kk = idx >> 7;
        bpack[(size_t)(kk * 32 + ich * 16 + icg) * 2048 + oc * 8 + j] =
            __float2bfloat16(ls[(icg * 8 + j) * 81 + kk]);
    }
}

// W_route fp32 [i1152][o10][d16][k8] -> W2 [o][ki=k*1152+i][d], via LDS; also zeroes bij.
__global__ __launch_bounds__(256) void build_w2(const float* __restrict__ Wr, float* __restrict__ W2,
                                                float* __restrict__ bij){
    __shared__ float ls[15360];                 // 12 i x 1280
    int bid = blockIdx.x;
    int i0 = bid * 12, t = threadIdx.x;
    const float4* src = (const float4*)(Wr + (size_t)i0 * 1280);
    for (int w = t; w < 3840; w += 256) ((float4*)ls)[w] = src[w];
    if (t < 120) bij[bid * 120 + t] = 0.f;      // 96*120 = 11520
    __syncthreads();
    for (int idx = t; idx < 15360; idx += 256){
        int d = idx & 15, r = idx >> 4;
        int il = r % 12, ok = r / 12;           // ok = o*8+k
        int k = ok & 7, o = ok >> 3;
        W2[(size_t)o * 147456 + (size_t)(k * 1152 + i0 + il) * 16 + d] =
            ls[il * 1280 + o * 128 + d * 8 + k];
    }
}

// conv1 as MFMA implicit-GEMM (r13 verbatim): 112 px x 256 oc per block, K=96.
__global__ __launch_bounds__(256) void conv1_mfma(const float* __restrict__ x,
                                                  const __hip_bfloat16* __restrict__ wpack1,
                                                  const float* __restrict__ bias,
                                                  __hip_bfloat16* __restrict__ hT){
    __shared__ ushort_t xs[784];
    __shared__ ushort_t ktab[96];
    int bid = blockIdx.x;
    int b = bid >> 2, mc = bid & 3;
    int t = threadIdx.x, lane = t & 63, wn = t >> 6;
    int g = lane >> 4, lr = lane & 15;

    for (int i = t; i < 784; i += 256) xs[i] = f2bu(x[b * 784 + i]);
    if (t < 96) ktab[t] = (t < 81) ? (ushort_t)((t / 9) * 28 + (t % 9)) : (ushort_t)0;
    __syncthreads();

    int p0 = mc * 112;
    int pbm[7];
#pragma unroll
    for (int m = 0; m < 7; m++){
        int p = p0 + m * 16 + lr;
        p = p < 400 ? p : 399;
        pbm[m] = (p / 20) * 28 + (p % 20);
    }

    f32x4 acc[7][4];
#pragma unroll
    for (int m = 0; m < 7; m++)
#pragma unroll
        for (int n = 0; n < 4; n++) acc[m][n] = (f32x4){0.f, 0.f, 0.f, 0.f};

#pragma unroll
    for (int ks = 0; ks < 3; ks++){
        short8 ko = *(const short8*)&ktab[ks * 32 + g * 8];
        short8 bf[4];
#pragma unroll
        for (int n = 0; n < 4; n++)
            bf[n] = *(const short8*)(wpack1 + (size_t)(((ks * 4 + g) * 256) + wn * 64 + n * 16 + lr) * 8);
#pragma unroll
        for (int m = 0; m < 7; m++){
            short8 af;
#pragma unroll
            for (int e = 0; e < 8; e++)
                af[e] = (short)xs[pbm[m] + (int)(ushort_t)ko[e]];
#pragma unroll
            for (int n = 0; n < 4; n++)
                acc[m][n] = __builtin_amdgcn_mfma_f32_16x16x32_bf16(af, bf[n], acc[m][n], 0, 0, 0);
        }
    }

    float bv[4];
#pragma unroll
    for (int n = 0; n < 4; n++) bv[n] = bias[wn * 64 + n * 16 + lr];
#pragma unroll
    for (int m = 0; m < 7; m++){
#pragma unroll
        for (int rg = 0; rg < 4; rg++){
            int p = p0 + m * 16 + g * 4 + rg;
            if (p < 400){
#pragma unroll
                for (int n = 0; n < 4; n++){
                    float v = acc[m][n][rg] + bv[n];
                    v = v > 0.f ? v : 0.f;
                    hT[((size_t)b * 400 + p) * 256 + wn * 64 + n * 16 + lr] = __float2bfloat16(v);
                }
            }
        }
    }
}

// Implicit-GEMM capsconv — r23 verbatim (79.7 us): XCD remap + T5 setprio + bf16 part.
__global__ __launch_bounds__(256, 2) void capsconv_mfma(const __hip_bfloat16* __restrict__ hT,
                                                        const __hip_bfloat16* __restrict__ bpack,
                                                        ushort_t* __restrict__ partb){
    extern __shared__ char smem[];               // 61440 B
    ushort_t* hsA = (ushort_t*)smem;

    int bid = blockIdx.x;
    int idx = (bid & 7) * 51 + (bid >> 3);
    if (idx >= 405) return;
    int mt = idx / 9, ky = idx - mt * 9;
    int b0 = mt * 4;
    int t = threadIdx.x, lane = t & 63, wn = t >> 6;
    int g = lane >> 4, lr = lane & 15;

    int pfm[9];
#pragma unroll
    for (int m = 0; m < 9; m++){
        int R = m * 16 + lr;
        int lb = R / 36, pos = R - lb * 36;
        int oy = pos / 6, ox = pos - oy * 6;
        int yy = lb * 6 + oy;
        pfm[m] = ((yy * 20 + 2 * ox) << 8) | (ox + 6 * yy);
    }
    int gbase = g * 2048 + wn * 512 + lr * 8;    // B lane offset (bf16 elems)

    auto stageA = [&](int a){
#pragma unroll
        for (int rnd = 0; rnd < 15; rnd++){
            int L = rnd * 256 + t;               // granule 0..3839
            int p = L >> 3, sg = L & 7;
            int yy = p / 20, xx = p - yy * 20;
            int lb = yy / 6;
            int y = ky + 2 * (yy - lb * 6);
            int f = ((xx >> 1) + 6 * yy) & 7;
            const __hip_bfloat16* src = hT + ((size_t)(((b0 + lb) * 20 + y) * 20 + xx) * 256
                                             + a * 64 + 8 * (sg ^ f));
            gload16(src, hsA + (size_t)(rnd * 256 + (t & ~63)) * 8);
        }
    };

    f32x4 acc[9][4];
#pragma unroll
    for (int m = 0; m < 9; m++)
#pragma unroll
        for (int n = 0; n < 4; n++) acc[m][n] = (f32x4){0.f, 0.f, 0.f, 0.f};

    stageA(0);
    __syncthreads();

    for (int a = 0; a < 4; a++){
#pragma unroll 2
        for (int r = 0; r < 18; r++){
            int kx = r >> 1, ics = r & 1;
            int ksg = (ky * 9 + kx) * 8 + 2 * a + ics;   // wave-uniform
            const __hip_bfloat16* bstep = bpack + (size_t)ksg * 8192 + gbase;
            short8 bf[4];
#pragma unroll
            for (int n = 0; n < 4; n++)
                bf[n] = *(const short8*)(bstep + n * 128);
            int jj = ics * 4 + g;
            __builtin_amdgcn_s_setprio(1);       // T5
#pragma unroll
            for (int m = 0; m < 9; m++){
                int pf = pfm[m];
                int p = (pf >> 8) + kx;
                int f = ((pf & 255) + (kx >> 1)) & 7;
                short8 af = *(const short8*)(hsA + (size_t)(p * 8 + (jj ^ f)) * 8);
#pragma unroll
                for (int n = 0; n < 4; n++)
                    acc[m][n] = __builtin_amdgcn_mfma_f32_16x16x32_bf16(af, bf[n], acc[m][n], 0, 0, 0);
            }
            __builtin_amdgcn_s_setprio(0);
        }
        if (a < 3){
            __syncthreads();     // all waves done reading chunk a
            stageA(a + 1);
            __syncthreads();     // drains gload16s + visibility
        }
    }

    // Epilogue: per-lb LDS transpose tile tl[pos 36][oc 260]; bf16 stores (8B ushort4).
    float* tl = (float*)smem;
    size_t pbase = ((size_t)ky * 180 + b0) * 9216;
    for (int lb = 0; lb < 4; lb++){
        int rlo = lb * 36;
        __syncthreads();
#pragma unroll
        for (int m = 0; m < 9; m++){
#pragma unroll
            for (int n = 0; n < 4; n++){
                int oc = wn * 64 + n * 16 + lr;
#pragma unroll
                for (int rg = 0; rg < 4; rg++){
                    int row = m * 16 + g * 4 + rg;
                    if (row >= rlo && row < rlo + 36)
                        tl[(row - rlo) * 260 + oc] = acc[m][n][rg];
                }
            }
        }
        __syncthreads();
#pragma unroll
        for (int j = 0; j < 9; j++){
            int pos = j * 4;
            ushort4_t sv;
            sv.x = f2bu(tl[(pos    ) * 260 + t]);
            sv.y = f2bu(tl[(pos + 1) * 260 + t]);
            sv.z = f2bu(tl[(pos + 2) * 260 + t]);
            sv.w = f2bu(tl[(pos + 3) * 260 + t]);
            *(ushort4_t*)&partb[pbase + (size_t)lb * 9216 + t * 36 + pos] = sv;
        }
    }
}

// reduce 9 bf16 ky-partials + bias, squash over each (b,k) 1152-block, COALESCED write to u[b][ki].
__global__ __launch_bounds__(192) void reduce_squash(const ushort_t* __restrict__ partb,
                                                     const float* __restrict__ caps_b,
                                                     float* __restrict__ u){
    __shared__ float red[3];
    int bk = blockIdx.x;
    int b = bk >> 3, k = bk & 7;
    int t = threadIdx.x;
    size_t base = (size_t)k * 1152;
    float vals[6];
    float ssq = 0.f;
#pragma unroll
    for (int j = 0; j < 6; j++){
        int i = t + j * 192;
        int oc = k * 32 + i / 36;
        float v = caps_b[oc];
#pragma unroll
        for (int kyi = 0; kyi < 9; kyi++)
            v += bu2f(partb[(size_t)(kyi * 180 + b) * 9216 + base + i]);
        vals[j] = v; ssq += v * v;
    }
#pragma unroll
    for (int off = 32; off; off >>= 1) ssq += __shfl_down(ssq, off, 64);
    if ((t & 63) == 0) red[t >> 6] = ssq;
    __syncthreads();
    float tot = red[0] + red[1] + red[2];
    float scale = 1.f / (sqrtf(tot) + tot);
#pragma unroll
    for (int j = 0; j < 6; j++)
        u[(size_t)b * 9216 + base + t + j * 192] = vals[j] * scale;
}

// u [b][ki=9216] fp32 -> uTb [ki][b=180] bf16, coalesced 32x32 tiles.
__global__ __launch_bounds__(1024) void transpose_u(const float* __restrict__ u, ushort_t* __restrict__ uTb){
    __shared__ float tile[32][33];
    int ki0 = blockIdx.x * 32, b0 = blockIdx.y * 32;
    int tx = threadIdx.x, ty = threadIdx.y;
    int b = b0 + ty;
    if (b < NB) tile[ty][tx] = u[(size_t)b * 9216 + ki0 + tx];
    __syncthreads();
    int bw = b0 + tx;
    if (bw < NB) uTb[(size_t)(ki0 + ty) * NB + bw] = f2bu(tile[tx][ty]);
}

// split-K s-partials, softmax fused in; paired-o blocks; uT in bf16. (r23 verbatim)
__global__ __launch_bounds__(384) void s_partial2(const float* __restrict__ W2, const ushort_t* __restrict__ uTb,
                                                  const float* __restrict__ bij, float* __restrict__ part72,
                                                  int first){
    __shared__ float ws2[2][2048];
    __shared__ float cs[2][128];
    int op = blockIdx.x, kc = blockIdx.y, t = threadIdx.x;
    int grp = t / 192, tg = t - grp * 192;
    int o = op * 2 + grp;
    const float4* src = (const float4*)(W2 + (size_t)o * 147456 + (size_t)kc * 2048);
    for (int w = tg; w < 512; w += 192) ((float4*)ws2[grp])[w] = src[w];
    if (tg < 128){
        if (first){
            cs[grp][tg] = 0.1f;
        } else {
            int ki = kc * 128 + tg;
            int i = ki - (ki / 1152) * 1152;
            const float* bp = bij + (size_t)i * 10;
            float v[10]; float mx = -1e30f;
#pragma unroll
            for (int q = 0; q < 10; q++){ v[q] = bp[q]; mx = fmaxf(mx, v[q]); }
            float sum = 0.f;
#pragma unroll
            for (int q = 0; q < 10; q++){ v[q] = __expf(v[q] - mx); sum += v[q]; }
            cs[grp][tg] = v[o] / sum;
        }
    }
    __syncthreads();
    if (tg < NB){
        f32x4 a0 = {0,0,0,0}, a1 = {0,0,0,0}, a2 = {0,0,0,0}, a3 = {0,0,0,0};
        const ushort_t* up = uTb + (size_t)kc * 128 * NB + tg;
        const float* w2g = ws2[grp];
        const float* csg = cs[grp];
#pragma unroll 4
        for (int j = 0; j < 128; j++){
            float tmp = bu2f(up[j * NB]) * csg[j];
            const f32x4* wp = (const f32x4*)(w2g + j * 16);
            a0 += tmp * wp[0]; a1 += tmp * wp[1]; a2 += tmp * wp[2]; a3 += tmp * wp[3];
        }
        f32x4* pp = (f32x4*)(part72 + ((size_t)kc * NB + tg) * 160 + o * 16);
        pp[0] = a0; pp[1] = a1; pp[2] = a2; pp[3] = a3;
    }
}

// fused: s[b][od] = sum_kc part72[kc][b][od] ; v = s / (sqrt(msq)+msq), msq over o. (r23 verbatim)
__global__ __launch_bounds__(192) void sred_vsq(const float* __restrict__ part72, float* __restrict__ v){
    __shared__ float sv[160];
    __shared__ float sc[16];
    int b = blockIdx.x, t = threadIdx.x;
    float s = 0.f;
    if (t < 160){
        const float* pp = part72 + (size_t)b * 160 + t;
        for (int kc = 0; kc < 72; kc++)
            s += pp[(size_t)kc * NB * 160];
        sv[t] = s;
    }
    __syncthreads();
    if (t < 16){
        float m = 0.f;
#pragma unroll
        for (int o = 0; o < 10; o++){ float x = sv[o * 16 + t]; m += x * x; }
        sc[t] = 1.f / (sqrtf(m) + m);
    }
    __syncthreads();
    if (t < 160) v[b * 160 + t] = s * sc[t & 15];
}

// fused p_gemm + uv_contract: P-tile in regs, dot with W2, atomicAdd into bij. (r23 verbatim)
__global__ __launch_bounds__(320) void p_uv(const ushort_t* __restrict__ uTb, const float* __restrict__ v,
                                            const float* __restrict__ W2, float* __restrict__ bij){
    __shared__ float vs[60 * 160];
    int t = threadIdx.x;
    int o = t % 10, kil = t / 10;
    int ki = blockIdx.x * 32 + kil;
    float acc[16];
#pragma unroll
    for (int d = 0; d < 16; d++) acc[d] = 0.f;
    const ushort_t* up = uTb + (size_t)ki * NB;
    for (int b0 = 0; b0 < NB; b0 += 60){
        __syncthreads();
        for (int j = t; j < 9600; j += 320) vs[j] = v[b0 * 160 + j];
        __syncthreads();
        for (int b = 0; b < 60; b++){
            float uv = bu2f(up[b0 + b]);
            const float* vp = &vs[b * 160 + o * 16];
#pragma unroll
            for (int d = 0; d < 16; d++) acc[d] += uv * vp[d];
        }
    }
    const float4* wp = (const float4*)(W2 + (size_t)o * 147456 + (size_t)ki * 16);
    float dot = 0.f;
#pragma unroll
    for (int q = 0; q < 4; q++){
        float4 a = wp[q];
        dot += a.x * acc[q*4] + a.y * acc[q*4+1] + a.z * acc[q*4+2] + a.w * acc[q*4+3];
    }
    int i = ki % 1152;
    atomicAdd(&bij[i * 10 + o], dot * (1.0f / 180.0f));
}

extern "C" void kernel_launch(void* const* d_in, const int* in_sizes, int n_in,
                              void* d_out, int out_size, void* d_ws, size_t ws_size,
                              hipStream_t stream){
    const float* x       = (const float*)d_in[0];
    const float* conv1_w = (const float*)d_in[1];
    const float* conv1_b = (const float*)d_in[2];
    const float* caps_w  = (const float*)d_in[3];
    const float* caps_b  = (const float*)d_in[4];
    const float* Wr      = (const float*)d_in[5];
    float* out = (float*)d_out;

    char* wsb = (char*)d_ws;
    __hip_bfloat16* hTb   = (__hip_bfloat16*)wsb;                  // 36,864,000 B
    __hip_bfloat16* bpack = (__hip_bfloat16*)(wsb + 36864000);     // 10,616,832 B
    ushort_t* partb = (ushort_t*)(wsb + 36864000 + 10616832);      // 29,859,840 B (bf16)
    float* u    = (float*)((char*)partb + 29859840);               //  6,635,520 B
    ushort_t* uTb = (ushort_t*)(u + 1658880);                      //  3,317,760 B (bf16)
    __hip_bfloat16* wpack1 = (__hip_bfloat16*)((char*)uTb + 3317760); // 49,152 B

    // routing scratch aliases 'partb' region (dead after reduce_squash + transpose_u)
    float* W2     = (float*)partb;            // 1,474,560 f (5.9 MB)
    float* part72 = W2 + 1474560;             // 2,073,600 f (8.3 MB)
    float* bij    = part72 + 2073600;         //    11,520 f   (total 14.2 MB < 29.9 MB)

    hipFuncSetAttribute((const void*)capsconv_mfma,
                        hipFuncAttributeMaxDynamicSharedMemorySize, 65536);

    build_bpack_t<<<dim3(256, 2), 256, 0, stream>>>(caps_w, bpack, conv1_w, wpack1);
    conv1_mfma<<<720, 256, 0, stream>>>(x, wpack1, conv1_b, hTb);
    capsconv_mfma<<<408, 256, 61440, stream>>>(hTb, bpack, partb);
    reduce_squash<<<1440, 192, 0, stream>>>(partb, caps_b, u);
    transpose_u<<<dim3(288, 6), dim3(32, 32), 0, stream>>>(u, uTb);
    build_w2<<<96, 256, 0, stream>>>(Wr, W2, bij);   // after partb is dead; also zeroes bij

    for (int it = 0; it < 3; ++it){
        s_partial2<<<dim3(5, 72), 384, 0, stream>>>(W2, uTb, bij, part72, it == 0 ? 1 : 0);
        sred_vsq<<<180, 192, 0, stream>>>(part72, out);
        if (it < 2)
            p_uv<<<288, 320, 0, stream>>>(uTb, out, W2, bij);
    }
}